// Round 15
// baseline (13798.537 us; speedup 1.0000x reference)
//
#include <hip/hip_runtime.h>
#include <hip/hip_bf16.h>

#define Tn 1024
#define Bn 128
#define INn 32
#define Hn 512
#define OUTn 32
#define Kn 64

typedef __attribute__((ext_vector_type(8))) __bf16 bf16x8;
typedef __attribute__((ext_vector_type(4))) float f32x4;
typedef __attribute__((ext_vector_type(4))) unsigned int u32x4;

typedef const __attribute__((address_space(1))) void* gas_p;
typedef __attribute__((address_space(3))) void* las_p;

static __device__ __forceinline__ float bf2f(unsigned short u) {
    union { unsigned int i; float f; } c; c.i = ((unsigned int)u) << 16; return c.f;
}
static __device__ __forceinline__ unsigned short f2bf(float f) {
    union { float f; unsigned int i; } c; c.f = f;
    unsigned int x = c.i;
    return (unsigned short)((x + 0x7fffu + ((x >> 16) & 1u)) >> 16);
}
static __device__ __forceinline__ float tanh_fast(float x) {
    float xc = fminf(fmaxf(x, -10.f), 10.f);
    float e = __expf(2.f * xc);
    return (e - 1.f) * __builtin_amdgcn_rcpf(e + 1.f);
}

// ---------------- f32 -> bf16 convert (n divisible by 4) ----------------
__global__ __launch_bounds__(256) void cvt_k(const float* __restrict__ in,
                                             unsigned short* __restrict__ out, int n4) {
    int i = blockIdx.x * 256 + threadIdx.x;
    if (i < n4) {
        float4 v = ((const float4*)in)[i];
        ushort4 o;
        o.x = f2bf(v.x); o.y = f2bf(v.y); o.z = f2bf(v.z); o.w = f2bf(v.w);
        ((ushort4*)out)[i] = o;
    }
}

// ---------------- pi coefficients + combined biases ----------------
__global__ __launch_bounds__(512) void prep_small(const float* __restrict__ b_d,
                                                  const float* __restrict__ bih0, const float* __restrict__ bhh0,
                                                  const float* __restrict__ bih1, const float* __restrict__ bhh1,
                                                  float* __restrict__ pi, float* __restrict__ bias0,
                                                  float* __restrict__ bias1) {
    int i = threadIdx.x;
    float d = 0.5f / (1.0f + expf(-b_d[i]));
    float c = 1.0f;
    for (int j = 1; j <= Kn; ++j) {
        c *= ((float)(j - 1) - d) / (float)j;
        pi[(j - 1) * Hn + i] = c;
    }
    bias0[i] = bih0[i] + bhh0[i];
    bias1[i] = bih1[i] + bhh1[i];
}

// ---------------- GEMM: C[M,N](bf16) = A[M,K](bf16) . Bm[N,K](bf16)^T + bias[N](f32) --------
// NOT in-place safe when C aliases A across blocks: ntile blocks share the same A row-panel
// (full K) while writing disjoint column slices of it -> cross-block race (round-14 lesson).
__global__ __launch_bounds__(256, 2) void gemm_bt(const unsigned short* __restrict__ A,
                                                  const unsigned short* __restrict__ Bm,
                                                  unsigned short* __restrict__ C,
                                                  const float* __restrict__ bias,
                                                  int M, int N, int K) {
    __shared__ unsigned short As[128 * 32];
    __shared__ unsigned short Bs[128 * 32];
    int ntile = N >> 7;
    int bm = blockIdx.x / ntile;
    int bn = blockIdx.x - bm * ntile;
    size_t m0 = (size_t)bm << 7;
    int n0 = bn << 7;
    int tid = threadIdx.x;
    int lane = tid & 63, w = tid >> 6;
    int wm = w >> 1, wn = w & 1;
    int r = lane & 15, g = lane >> 4;
    int srow = tid >> 2, sblk = tid & 3;
    f32x4 acc[4][4] = {};
    for (int k0 = 0; k0 < K; k0 += 32) {
#pragma unroll
        for (int it = 0; it < 2; ++it) {
            const unsigned short* ga = A + (m0 + it * 64 + srow) * (size_t)K + k0 + sblk * 8;
            __builtin_amdgcn_global_load_lds((gas_p)ga, (las_p)((char*)As + it * 4096 + w * 1024), 16, 0, 0);
            const unsigned short* gbp = Bm + ((size_t)(n0 + it * 64 + srow)) * (size_t)K + k0 + sblk * 8;
            __builtin_amdgcn_global_load_lds((gas_p)gbp, (las_p)((char*)Bs + it * 4096 + w * 1024), 16, 0, 0);
        }
        __syncthreads();
        bf16x8 af[4], bfr[4];
#pragma unroll
        for (int m = 0; m < 4; ++m) af[m] = *(const bf16x8*)&As[(wm * 64 + m * 16 + r) * 32 + g * 8];
#pragma unroll
        for (int n = 0; n < 4; ++n) bfr[n] = *(const bf16x8*)&Bs[(wn * 64 + n * 16 + r) * 32 + g * 8];
#pragma unroll
        for (int m = 0; m < 4; ++m)
#pragma unroll
            for (int n = 0; n < 4; ++n)
                acc[m][n] = __builtin_amdgcn_mfma_f32_16x16x32_bf16(af[m], bfr[n], acc[m][n], 0, 0, 0);
        __syncthreads();
    }
#pragma unroll
    for (int n = 0; n < 4; ++n) {
        int col = n0 + wn * 64 + n * 16 + r;
        float bv = bias[col];
#pragma unroll
        for (int m = 0; m < 4; ++m) {
            size_t row0 = m0 + wm * 64 + m * 16 + g * 4;
#pragma unroll
            for (int q = 0; q < 4; ++q)
                C[(row0 + q) * (size_t)N + col] = f2bf(acc[m][n][q] + bv);
        }
    }
}

// ---------------- causal fractional-diff filter (chunked over t) ----------------
__global__ __launch_bounds__(256, 2) void filt_k(const unsigned short* __restrict__ X,
                                                 const float* __restrict__ Pi,
                                                 unsigned short* __restrict__ Y, int t_off) {
    int tid = threadIdx.x;
    int il = tid & 63, ts = tid >> 6;
    int i = blockIdx.x * 64 + il;
    int b = blockIdx.z;
    int tbase = t_off + blockIdx.y * 128 + ts * 32;
    float xr[96];
#pragma unroll
    for (int k2 = 0; k2 < 96; ++k2) {
        int t = tbase - 64 + k2;
        xr[k2] = (t >= 0) ? bf2f(X[(size_t)t * (Bn * Hn) + b * Hn + i]) : 0.0f;
    }
    float acc[32];
#pragma unroll
    for (int tt = 0; tt < 32; ++tt) acc[tt] = xr[64 + tt];
#pragma unroll
    for (int j = 1; j <= 64; ++j) {
        float p = Pi[(j - 1) * Hn + i];
#pragma unroll
        for (int tt = 0; tt < 32; ++tt) acc[tt] += p * xr[64 + tt - j];
    }
#pragma unroll
    for (int tt = 0; tt < 32; ++tt)
        Y[(size_t)(tbase - t_off + tt) * (Bn * Hn) + b * Hn + i] = f2bf(acc[tt]);
}

// ---------------- recurrence v16: BARRIER-FREE waves, W in LDS, per-thread frag polls ------
// 32 wgs = 8 gb x 4 oq (128-o quarters); bid = gb + 8*oq -> all partners of a gb on one
// XCD (round-robin heuristic, perf only). 256 thr = 4 waves; wave w owns o-rows
// [oq*128 + w*32, +32). W slice [128][512] in LDS (128KB), staged once (swizzled chunks
// c^(row&7), bank-uniform 8 dwords/bank for all reads), ONE barrier total.
// Per step each THREAD polls exactly its own MFMA B-fragments from ex: h[b=r][all k] =
// 512 tagged u32 = 32 dwordx4 (disjoint across lanes; per-16-u32-block done-mask retry
// with s_sleep backoff). NO h LDS, NO per-step barriers: waves free-run on data deps,
// so one late producer no longer stalls 8 waves at 2 barriers (rec7/14's amplification).
// ex: u32[2 par][8 gb][16 b][512 o], val=(bf16<<16)|(fbase+t+1). Overwrite safety: a
// producer publishes V only after consuming all producers' V-1, which they published
// only after consuming V-2 -> slot V&1 (holding V-2) is globally dead. memset/launch.
__global__ __launch_bounds__(256, 1) void rec16_k(const unsigned short* __restrict__ W,
                                                  const unsigned short* pre,
                                                  unsigned short* hs,
                                                  float* __restrict__ hfin,
                                                  unsigned int* ex, int fbase) {
    __shared__ unsigned short Wl[128 * 512];
    int bid = blockIdx.x;
    int gb = bid & 7, oq = bid >> 3;
    int tid = threadIdx.x, lane = tid & 63, w = tid >> 6;
    int r = lane & 15, g = lane >> 4;
    int rx = r & 7;
    int lr0 = w * 32 + r, lr1 = w * 32 + 16 + r;
    int ob0 = oq * 128 + w * 32;
    // stage W rows [oq*128, +128): linear LDS dest, pre-swizzled per-lane global source
#pragma unroll
    for (int it = 0; it < 32; ++it) {
        int row = it * 4 + w;
        const unsigned short* gsrc = W + (size_t)(oq * 128 + row) * Hn + (size_t)((lane ^ (row & 7)) * 8);
        __builtin_amdgcn_global_load_lds((gas_p)gsrc, (las_p)((char*)Wl + row * 1024), 16, 0, 0);
    }
    int bb = gb * 16 + r;
    const unsigned short* preP = pre + (size_t)bb * Hn + ob0 + g * 4;
    unsigned short* hsP = hs ? hs + (size_t)bb * Hn + ob0 + g * 4 : (unsigned short*)0;
    __syncthreads();                       // W staged; the ONLY barrier
    unsigned long long pfA0 = *(const unsigned long long*)(preP);
    unsigned long long pfA1 = *(const unsigned long long*)(preP + 16);
    unsigned long long pfB0 = *(const unsigned long long*)(preP + (size_t)(Bn * Hn));
    unsigned long long pfB1 = *(const unsigned long long*)(preP + (size_t)(Bn * Hn) + 16);

#define PACK2(E, O) (((E) >> 16) | ((O) & 0xffff0000u))
#define ISSUEB(Q0, Q1, Q2, Q3, O0, O1, O2, O3)                                                \
    asm volatile("global_load_dwordx4 %0, %4, off offset:" #O0 " sc1\n\t"                     \
                 "global_load_dwordx4 %1, %4, off offset:" #O1 " sc1\n\t"                     \
                 "global_load_dwordx4 %2, %4, off offset:" #O2 " sc1\n\t"                     \
                 "global_load_dwordx4 %3, %4, off offset:" #O3 " sc1"                         \
                 : "=v"(Q0), "=v"(Q1), "=v"(Q2), "=v"(Q3) : "v"(vp) : "memory")
#define CHKB(J, Q0, Q1, Q2, Q3)                                                               \
    if (!(nd & (1u << J))) {                                                                  \
        unsigned m_ = (Q0.x ^ tg) | (Q0.y ^ tg) | (Q0.z ^ tg) | (Q0.w ^ tg) |                 \
                      (Q1.x ^ tg) | (Q1.y ^ tg) | (Q1.z ^ tg) | (Q1.w ^ tg) |                 \
                      (Q2.x ^ tg) | (Q2.y ^ tg) | (Q2.z ^ tg) | (Q2.w ^ tg) |                 \
                      (Q3.x ^ tg) | (Q3.y ^ tg) | (Q3.z ^ tg) | (Q3.w ^ tg);                  \
        if (!(m_ & 0xffffu)) nd |= (1u << J);                                                 \
    }
#define FRAG(KK, QA, QB)                                                                      \
    {                                                                                         \
        union { unsigned int u[4]; bf16x8 v; } hb_;                                          \
        hb_.u[0] = PACK2(QA.x, QA.y); hb_.u[1] = PACK2(QA.z, QA.w);                           \
        hb_.u[2] = PACK2(QB.x, QB.y); hb_.u[3] = PACK2(QB.z, QB.w);                           \
        bf16x8 wf0_ = *(const bf16x8*)&Wl[lr0 * 512 + ((((KK) * 4 + g) ^ rx) << 3)];          \
        bf16x8 wf1_ = *(const bf16x8*)&Wl[lr1 * 512 + ((((KK) * 4 + g) ^ rx) << 3)];          \
        acc0 = __builtin_amdgcn_mfma_f32_16x16x32_bf16(wf0_, hb_.v, acc0, 0, 0, 0);           \
        acc1 = __builtin_amdgcn_mfma_f32_16x16x32_bf16(wf1_, hb_.v, acc1, 0, 0, 0);           \
    }

#define REC_STEP(TT, P0, P1, ISLAST)                                                             \
    {                                                                                            \
        const int p = TT & 1;                                                                    \
        unsigned tg = (unsigned)(fbase + TT);                                                    \
        f32x4 acc0 = {0.f, 0.f, 0.f, 0.f}, acc1 = {0.f, 0.f, 0.f, 0.f};                          \
        u32x4 q00, q01, q02, q03, q10, q11, q12, q13, q20, q21, q22, q23, q30, q31, q32, q33;    \
        u32x4 q40, q41, q42, q43, q50, q51, q52, q53, q60, q61, q62, q63, q70, q71, q72, q73;    \
        if (TT > 0) {                                                                            \
            const unsigned int* vp = ex + ((size_t)p * 8 + gb) * 8192 + r * 512 + g * 8;         \
            ISSUEB(q00, q01, q02, q03, 0, 16, 128, 144);                                         \
            ISSUEB(q10, q11, q12, q13, 256, 272, 384, 400);                                      \
            ISSUEB(q20, q21, q22, q23, 512, 528, 640, 656);                                      \
            ISSUEB(q30, q31, q32, q33, 768, 784, 896, 912);                                      \
            ISSUEB(q40, q41, q42, q43, 1024, 1040, 1152, 1168);                                  \
            ISSUEB(q50, q51, q52, q53, 1280, 1296, 1408, 1424);                                  \
            ISSUEB(q60, q61, q62, q63, 1536, 1552, 1664, 1680);                                  \
            ISSUEB(q70, q71, q72, q73, 1792, 1808, 1920, 1936);                                  \
            unsigned done = 0;                                                                   \
            while (done != 0xffu) {                                                              \
                asm volatile("s_waitcnt vmcnt(0)" ::: "memory");                                 \
                __builtin_amdgcn_sched_barrier(0);                                               \
                unsigned nd = done;                                                              \
                CHKB(0, q00, q01, q02, q03) CHKB(1, q10, q11, q12, q13)                          \
                CHKB(2, q20, q21, q22, q23) CHKB(3, q30, q31, q32, q33)                          \
                CHKB(4, q40, q41, q42, q43) CHKB(5, q50, q51, q52, q53)                          \
                CHKB(6, q60, q61, q62, q63) CHKB(7, q70, q71, q72, q73)                          \
                if (nd == done) __builtin_amdgcn_s_sleep(2);                                     \
                if (nd != 0xffu) {                                                               \
                    if (!(nd & 1u))   ISSUEB(q00, q01, q02, q03, 0, 16, 128, 144);               \
                    if (!(nd & 2u))   ISSUEB(q10, q11, q12, q13, 256, 272, 384, 400);            \
                    if (!(nd & 4u))   ISSUEB(q20, q21, q22, q23, 512, 528, 640, 656);            \
                    if (!(nd & 8u))   ISSUEB(q30, q31, q32, q33, 768, 784, 896, 912);            \
                    if (!(nd & 16u))  ISSUEB(q40, q41, q42, q43, 1024, 1040, 1152, 1168);        \
                    if (!(nd & 32u))  ISSUEB(q50, q51, q52, q53, 1280, 1296, 1408, 1424);        \
                    if (!(nd & 64u))  ISSUEB(q60, q61, q62, q63, 1536, 1552, 1664, 1680);        \
                    if (!(nd & 128u)) ISSUEB(q70, q71, q72, q73, 1792, 1808, 1920, 1936);        \
                }                                                                                \
                done = nd;                                                                       \
            }                                                                                    \
            __builtin_amdgcn_sched_barrier(0);                                                   \
            FRAG(0, q00, q01)  FRAG(1, q02, q03)  FRAG(2, q10, q11)  FRAG(3, q12, q13)           \
            FRAG(4, q20, q21)  FRAG(5, q22, q23)  FRAG(6, q30, q31)  FRAG(7, q32, q33)           \
            FRAG(8, q40, q41)  FRAG(9, q42, q43)  FRAG(10, q50, q51) FRAG(11, q52, q53)          \
            FRAG(12, q60, q61) FRAG(13, q62, q63) FRAG(14, q70, q71) FRAG(15, q72, q73)          \
        }                                                                                        \
        /* prefetch pre[TT+2] after the poll (keeps next poll's vmcnt(0) near-drained) */        \
        int tn = (TT + 2 < Tn) ? TT + 2 : Tn - 1;                                                \
        unsigned long long n0 = *(const unsigned long long*)(preP + (size_t)tn * (Bn * Hn));     \
        unsigned long long n1 = *(const unsigned long long*)(preP + (size_t)tn * (Bn * Hn) + 16);\
        union { unsigned long long u; unsigned short s[4]; } p0, p1;                             \
        p0.u = P0; p1.u = P1;                                                                    \
        float h0 = tanh_fast(acc0[0] + bf2f(p0.s[0]));                                           \
        float h1 = tanh_fast(acc0[1] + bf2f(p0.s[1]));                                           \
        float h2 = tanh_fast(acc0[2] + bf2f(p0.s[2]));                                           \
        float h3 = tanh_fast(acc0[3] + bf2f(p0.s[3]));                                           \
        float h4 = tanh_fast(acc1[0] + bf2f(p1.s[0]));                                           \
        float h5 = tanh_fast(acc1[1] + bf2f(p1.s[1]));                                           \
        float h6 = tanh_fast(acc1[2] + bf2f(p1.s[2]));                                           \
        float h7 = tanh_fast(acc1[3] + bf2f(p1.s[3]));                                           \
        unsigned int b0 = f2bf(h0), b1 = f2bf(h1), b2 = f2bf(h2), b3 = f2bf(h3);                 \
        unsigned int b4 = f2bf(h4), b5 = f2bf(h5), b6 = f2bf(h6), b7 = f2bf(h7);                 \
        unsigned tv = tg + 1u;                                                                   \
        u32x4 s0 = { (b0 << 16) | tv, (b1 << 16) | tv, (b2 << 16) | tv, (b3 << 16) | tv };       \
        u32x4 s1 = { (b4 << 16) | tv, (b5 << 16) | tv, (b6 << 16) | tv, (b7 << 16) | tv };       \
        unsigned int* wp = ex + ((size_t)((TT + 1) & 1) * 8 + gb) * 8192 + r * 512 + ob0 + g * 4;\
        asm volatile("global_store_dwordx4 %0, %1, off sc1\n\t"                                  \
                     "global_store_dwordx4 %0, %2, off offset:64 sc1"                            \
                     :: "v"(wp), "v"(s0), "v"(s1) : "memory");                                   \
        if (hsP) {                                                                               \
            union { unsigned int u[2]; unsigned long long v; } o0, o1;                           \
            o0.u[0] = b0 | (b1 << 16); o0.u[1] = b2 | (b3 << 16);                                \
            o1.u[0] = b4 | (b5 << 16); o1.u[1] = b6 | (b7 << 16);                                \
            *(unsigned long long*)(hsP + (size_t)TT * (Bn * Hn)) = o0.v;                         \
            *(unsigned long long*)(hsP + (size_t)TT * (Bn * Hn) + 16) = o1.v;                    \
        }                                                                                        \
        if (ISLAST && hfin) {                                                                    \
            float* hf = hfin + (size_t)bb * Hn + ob0 + g * 4;                                    \
            hf[0] = h0; hf[1] = h1; hf[2] = h2; hf[3] = h3;                                      \
            hf[16] = h4; hf[17] = h5; hf[18] = h6; hf[19] = h7;                                  \
        }                                                                                        \
        P0 = n0; P1 = n1;                                                                        \
    }

    for (int t = 0; t < Tn; t += 2) {
        REC_STEP(t, pfA0, pfA1, false)
        REC_STEP((t + 1), pfB0, pfB1, (t + 1 == Tn - 1))
    }
#undef REC_STEP
#undef FRAG
#undef CHKB
#undef ISSUEB
#undef PACK2
}

// ---------------- final readout ----------------
__global__ __launch_bounds__(64) void readout_k(const float* __restrict__ hfin,
                                                const float* __restrict__ Who1,
                                                const float* __restrict__ bho1,
                                                float* __restrict__ out) {
    int b = blockIdx.x;
    __shared__ float hv[Hn];
    int tid = threadIdx.x;
    for (int i = tid; i < Hn; i += 64) hv[i] = hfin[(size_t)b * Hn + i];
    __syncthreads();
    if (tid < OUTn) {
        float acc = bho1[tid];
        const float* wrow = Who1 + (size_t)tid * Hn;
#pragma unroll 8
        for (int i = 0; i < Hn; ++i) acc += wrow[i] * hv[i];
        out[b * OUTn + tid] = acc;
    }
}

extern "C" void kernel_launch(void* const* d_in, const int* in_sizes, int n_in,
                              void* d_out, int out_size, void* d_ws, size_t ws_size,
                              hipStream_t stream) {
    const float* inputs = (const float*)d_in[0];
    const float* b_d    = (const float*)d_in[1];
    const float* W_emb  = (const float*)d_in[2];
    const float* b_emb  = (const float*)d_in[3];
    const float* W_ih0  = (const float*)d_in[4];
    const float* b_ih0  = (const float*)d_in[5];
    const float* W_hh0  = (const float*)d_in[6];
    const float* b_hh0  = (const float*)d_in[7];
    const float* W_ho0  = (const float*)d_in[8];
    const float* b_ho0  = (const float*)d_in[9];
    const float* W_ih1  = (const float*)d_in[10];
    const float* b_ih1  = (const float*)d_in[11];
    const float* W_hh1  = (const float*)d_in[12];
    const float* b_hh1  = (const float*)d_in[13];
    const float* W_ho1  = (const float*)d_in[14];
    const float* b_ho1  = (const float*)d_in[15];

    char* ws = (char*)d_ws;
    size_t off = 0;
    auto alloc = [&](size_t bytes) {
        void* p = ws + off;
        off += (bytes + 255) & ~(size_t)255;
        return p;
    };
    unsigned short* B    = (unsigned short*)alloc(134217728); // resident [T,B,H] bf16
    unsigned short* Hf   = (unsigned short*)alloc(67108864);  // half-T bounce
    unsigned short* inb  = (unsigned short*)alloc(8388608);
    unsigned short* Wemb = (unsigned short*)alloc(32768);
    unsigned short* Wih0 = (unsigned short*)alloc(524288);
    unsigned short* Whh0 = (unsigned short*)alloc(524288);
    unsigned short* Who0 = (unsigned short*)alloc(524288);
    unsigned short* Wih1 = (unsigned short*)alloc(524288);
    unsigned short* Whh1 = (unsigned short*)alloc(524288);
    float* bias0 = (float*)alloc(2048);
    float* bias1 = (float*)alloc(2048);
    float* piB   = (float*)alloc(131072);
    unsigned int* ex = (unsigned int*)alloc(524288);          // [2][8][16][512] u32
    float* hfin = (float*)alloc(262144);
    (void)ws_size; (void)in_sizes; (void)n_in; (void)out_size;

    unsigned short* B_hi = B + (size_t)512 * Bn * Hn;
    const size_t halfBytes = 67108864;
    const int Mh = 512 * Bn;

    hipMemsetAsync(ex, 0, 524288, stream);
    cvt_k<<<4096, 256, 0, stream>>>(inputs, inb, 1048576);
    cvt_k<<<16,   256, 0, stream>>>(W_emb, Wemb, 4096);
    cvt_k<<<256,  256, 0, stream>>>(W_ih0, Wih0, 65536);
    cvt_k<<<256,  256, 0, stream>>>(W_hh0, Whh0, 65536);
    cvt_k<<<256,  256, 0, stream>>>(W_ho0, Who0, 65536);
    cvt_k<<<256,  256, 0, stream>>>(W_ih1, Wih1, 65536);
    cvt_k<<<256,  256, 0, stream>>>(W_hh1, Whh1, 65536);
    prep_small<<<1, 512, 0, stream>>>(b_d, b_ih0, b_hh0, b_ih1, b_hh1, piB, bias0, bias1);

    // ---- layer 0 ----
    gemm_bt<<<4096, 256, 0, stream>>>(inb, Wemb, B, b_emb, Tn * Bn, Hn, INn);    // B = x
    filt_k<<<dim3(8, 4, 128), 256, 0, stream>>>(B, piB, Hf, 512);
    gemm_bt<<<2048, 256, 0, stream>>>(Hf, Wih0, B_hi, bias0, Mh, Hn, Hn);        // B_hi = pre0_hi
    filt_k<<<dim3(8, 4, 128), 256, 0, stream>>>(B, piB, Hf, 0);
    gemm_bt<<<2048, 256, 0, stream>>>(Hf, Wih0, B, bias0, Mh, Hn, Hn);           // B_lo = pre0_lo
    rec16_k<<<32, 256, 0, stream>>>(Whh0, B, B, nullptr, ex, 0);                 // B = hs0 (in place)
    // y0 = hs0 @ Who0^T via bounce (in-place across blocks is a race -- round-14 lesson)
    gemm_bt<<<2048, 256, 0, stream>>>(B_hi, Who0, Hf, b_ho0, Mh, Hn, Hn);
    hipMemcpyAsync(B_hi, Hf, halfBytes, hipMemcpyDeviceToDevice, stream);
    gemm_bt<<<2048, 256, 0, stream>>>(B, Who0, Hf, b_ho0, Mh, Hn, Hn);
    hipMemcpyAsync(B, Hf, halfBytes, hipMemcpyDeviceToDevice, stream);           // B = y0
    // ---- layer 1 ----
    filt_k<<<dim3(8, 4, 128), 256, 0, stream>>>(B, piB, Hf, 512);
    gemm_bt<<<2048, 256, 0, stream>>>(Hf, Wih1, B_hi, bias1, Mh, Hn, Hn);        // B_hi = pre1_hi
    filt_k<<<dim3(8, 4, 128), 256, 0, stream>>>(B, piB, Hf, 0);
    gemm_bt<<<2048, 256, 0, stream>>>(Hf, Wih1, B, bias1, Mh, Hn, Hn);           // B_lo = pre1_lo
    rec16_k<<<32, 256, 0, stream>>>(Whh1, B, nullptr, hfin, ex, 1024);
    readout_k<<<128, 64, 0, stream>>>(hfin, W_ho1, b_ho1, (float*)d_out);
}

// Round 16
// 5565.316 us; speedup vs baseline: 2.4794x; 2.4794x over previous
//
#include <hip/hip_runtime.h>
#include <hip/hip_bf16.h>

#define Tn 1024
#define Bn 128
#define INn 32
#define Hn 512
#define OUTn 32
#define Kn 64
#define LPAD 536

typedef __attribute__((ext_vector_type(8))) __bf16 bf16x8;
typedef __attribute__((ext_vector_type(4))) float f32x4;
typedef __attribute__((ext_vector_type(4))) unsigned int u32x4;
typedef __attribute__((ext_vector_type(2))) unsigned int u32x2;

typedef const __attribute__((address_space(1))) void* gas_p;
typedef __attribute__((address_space(3))) void* las_p;

static __device__ __forceinline__ float bf2f(unsigned short u) {
    union { unsigned int i; float f; } c; c.i = ((unsigned int)u) << 16; return c.f;
}
static __device__ __forceinline__ unsigned short f2bf(float f) {
    union { float f; unsigned int i; } c; c.f = f;
    unsigned int x = c.i;
    return (unsigned short)((x + 0x7fffu + ((x >> 16) & 1u)) >> 16);
}
static __device__ __forceinline__ float tanh_fast(float x) {
    float xc = fminf(fmaxf(x, -10.f), 10.f);
    float e = __expf(2.f * xc);
    return (e - 1.f) * __builtin_amdgcn_rcpf(e + 1.f);
}

// ---------------- f32 -> bf16 convert (n divisible by 4) ----------------
__global__ __launch_bounds__(256) void cvt_k(const float* __restrict__ in,
                                             unsigned short* __restrict__ out, int n4) {
    int i = blockIdx.x * 256 + threadIdx.x;
    if (i < n4) {
        float4 v = ((const float4*)in)[i];
        ushort4 o;
        o.x = f2bf(v.x); o.y = f2bf(v.y); o.z = f2bf(v.z); o.w = f2bf(v.w);
        ((ushort4*)out)[i] = o;
    }
}

// ---------------- pi coefficients + combined biases ----------------
__global__ __launch_bounds__(512) void prep_small(const float* __restrict__ b_d,
                                                  const float* __restrict__ bih0, const float* __restrict__ bhh0,
                                                  const float* __restrict__ bih1, const float* __restrict__ bhh1,
                                                  float* __restrict__ pi, float* __restrict__ bias0,
                                                  float* __restrict__ bias1) {
    int i = threadIdx.x;
    float d = 0.5f / (1.0f + expf(-b_d[i]));
    float c = 1.0f;
    for (int j = 1; j <= Kn; ++j) {
        c *= ((float)(j - 1) - d) / (float)j;
        pi[(j - 1) * Hn + i] = c;
    }
    bias0[i] = bih0[i] + bhh0[i];
    bias1[i] = bih1[i] + bhh1[i];
}

// ---------------- GEMM: C[M,N](bf16) = A[M,K](bf16) . Bm[N,K](bf16)^T + bias[N](f32) --------
__global__ __launch_bounds__(256, 2) void gemm_bt(const unsigned short* __restrict__ A,
                                                  const unsigned short* __restrict__ Bm,
                                                  unsigned short* __restrict__ C,
                                                  const float* __restrict__ bias,
                                                  int M, int N, int K) {
    __shared__ unsigned short As[128 * 32];
    __shared__ unsigned short Bs[128 * 32];
    int ntile = N >> 7;
    int bm = blockIdx.x / ntile;
    int bn = blockIdx.x - bm * ntile;
    size_t m0 = (size_t)bm << 7;
    int n0 = bn << 7;
    int tid = threadIdx.x;
    int lane = tid & 63, w = tid >> 6;
    int wm = w >> 1, wn = w & 1;
    int r = lane & 15, g = lane >> 4;
    int srow = tid >> 2, sblk = tid & 3;
    f32x4 acc[4][4] = {};
    for (int k0 = 0; k0 < K; k0 += 32) {
#pragma unroll
        for (int it = 0; it < 2; ++it) {
            const unsigned short* ga = A + (m0 + it * 64 + srow) * (size_t)K + k0 + sblk * 8;
            __builtin_amdgcn_global_load_lds((gas_p)ga, (las_p)((char*)As + it * 4096 + w * 1024), 16, 0, 0);
            const unsigned short* gbp = Bm + ((size_t)(n0 + it * 64 + srow)) * (size_t)K + k0 + sblk * 8;
            __builtin_amdgcn_global_load_lds((gas_p)gbp, (las_p)((char*)Bs + it * 4096 + w * 1024), 16, 0, 0);
        }
        __syncthreads();
        bf16x8 af[4], bfr[4];
#pragma unroll
        for (int m = 0; m < 4; ++m) af[m] = *(const bf16x8*)&As[(wm * 64 + m * 16 + r) * 32 + g * 8];
#pragma unroll
        for (int n = 0; n < 4; ++n) bfr[n] = *(const bf16x8*)&Bs[(wn * 64 + n * 16 + r) * 32 + g * 8];
#pragma unroll
        for (int m = 0; m < 4; ++m)
#pragma unroll
            for (int n = 0; n < 4; ++n)
                acc[m][n] = __builtin_amdgcn_mfma_f32_16x16x32_bf16(af[m], bfr[n], acc[m][n], 0, 0, 0);
        __syncthreads();
    }
#pragma unroll
    for (int n = 0; n < 4; ++n) {
        int col = n0 + wn * 64 + n * 16 + r;
        float bv = bias[col];
#pragma unroll
        for (int m = 0; m < 4; ++m) {
            size_t row0 = m0 + wm * 64 + m * 16 + g * 4;
#pragma unroll
            for (int q = 0; q < 4; ++q)
                C[(row0 + q) * (size_t)N + col] = f2bf(acc[m][n][q] + bv);
        }
    }
}

// ---------------- causal fractional-diff filter (chunked over t) ----------------
__global__ __launch_bounds__(256, 2) void filt_k(const unsigned short* __restrict__ X,
                                                 const float* __restrict__ Pi,
                                                 unsigned short* __restrict__ Y, int t_off) {
    int tid = threadIdx.x;
    int il = tid & 63, ts = tid >> 6;
    int i = blockIdx.x * 64 + il;
    int b = blockIdx.z;
    int tbase = t_off + blockIdx.y * 128 + ts * 32;
    float xr[96];
#pragma unroll
    for (int k2 = 0; k2 < 96; ++k2) {
        int t = tbase - 64 + k2;
        xr[k2] = (t >= 0) ? bf2f(X[(size_t)t * (Bn * Hn) + b * Hn + i]) : 0.0f;
    }
    float acc[32];
#pragma unroll
    for (int tt = 0; tt < 32; ++tt) acc[tt] = xr[64 + tt];
#pragma unroll
    for (int j = 1; j <= 64; ++j) {
        float p = Pi[(j - 1) * Hn + i];
#pragma unroll
        for (int tt = 0; tt < 32; ++tt) acc[tt] += p * xr[64 + tt - j];
    }
#pragma unroll
    for (int tt = 0; tt < 32; ++tt)
        Y[(size_t)(tbase - t_off + tt) * (Bn * Hn) + b * Hn + i] = f2bf(acc[tt]);
}

// ---------------- recurrence v18: rec14 + opaque-pin of wreg => true W register residency --
// IDENTICAL to round-12 rec14_k except: after loading wreg0/1, an empty inline-asm "+v"
// pin makes each fragment's origin opaque -> the allocator CANNOT rematerialize the W
// loads inside the t-loop (the 256 KB/step/CU L2 W-stream = ~4600 cy that dominated
// rec14's 5545 cy/step). Budget check: (512,1) -> 2 waves/SIMD -> 256 regs/wave;
// wreg 128 + acc 8 + poll 16 + addressing ~70 fits. Downside is diagnosable: scratch
// spill would show as +125MB WRITE_SIZE.
#define MFMA8(K0)                                                                              \
    {                                                                                          \
        _Pragma("unroll") for (int kk = 0; kk < 8; ++kk) {                                     \
            bf16x8 bf = *(const bf16x8*)(hrow + (K0 + kk) * 32 + g * 8);                       \
            acc0 = __builtin_amdgcn_mfma_f32_16x16x32_bf16(wreg0[K0 + kk], bf, acc0, 0, 0, 0); \
            acc1 = __builtin_amdgcn_mfma_f32_16x16x32_bf16(wreg1[K0 + kk], bf, acc1, 0, 0, 0); \
        }                                                                                      \
    }

__global__ __launch_bounds__(512, 1) void rec18_k(const unsigned short* __restrict__ W,
                                                  const unsigned short* pre,
                                                  unsigned short* hs,
                                                  float* __restrict__ hfin,
                                                  unsigned int* ex, int fbase) {
    __shared__ unsigned short hl[2][16][LPAD];
    int bid = blockIdx.x;
    int gb = bid & 7, go = bid >> 3;
    int tid = threadIdx.x, lane = tid & 63, w = tid >> 6;
    int r = lane & 15, g = lane >> 4;
    int ob = go * 256 + w * 32;
    bf16x8 wreg0[16], wreg1[16];
#pragma unroll
    for (int kk = 0; kk < 16; ++kk) {
        wreg0[kk] = *(const bf16x8*)(W + (size_t)(ob + r) * Hn + kk * 32 + g * 8);
        wreg1[kk] = *(const bf16x8*)(W + (size_t)(ob + 16 + r) * Hn + kk * 32 + g * 8);
    }
#pragma unroll
    for (int kk = 0; kk < 16; ++kk)
        asm volatile("" : "+v"(wreg0[kk]), "+v"(wreg1[kk]));   // pin: no remat of W loads
    int bb = gb * 16 + r;
    const unsigned short* preP = pre + (size_t)bb * Hn + ob + g * 4;
    unsigned short* hsP = hs ? hs + (size_t)bb * Hn + ob + g * 4 : (unsigned short*)0;
    int myblk = gb * 2 + go, pblk = gb * 2 + (go ^ 1);
    int pbatch = tid >> 5;
    int pcol = (go ^ 1) * 256 + (tid & 31) * 8;
    unsigned long long pfA0 = *(const unsigned long long*)(preP);
    unsigned long long pfA1 = *(const unsigned long long*)(preP + 16);
    unsigned long long pfB0 = *(const unsigned long long*)(preP + (size_t)(Bn * Hn));
    unsigned long long pfB1 = *(const unsigned long long*)(preP + (size_t)(Bn * Hn) + 16);

#define REC_STEP(TT, P0, P1, ISLAST)                                                             \
    {                                                                                            \
        asm volatile("s_waitcnt lgkmcnt(0)\n\ts_barrier" ::: "memory"); /* A: own half ready */  \
        f32x4 acc0 = {0.f, 0.f, 0.f, 0.f}, acc1 = {0.f, 0.f, 0.f, 0.f};                          \
        const unsigned short* hrow = &hl[TT & 1][r][0];                                          \
        if (TT > 0) {                                                                            \
            if (go == 0) MFMA8(0) else MFMA8(8)      /* phase 1: own half */                     \
            unsigned tg = (unsigned)(fbase + TT);                                                \
            const unsigned int* pp = ex + ((size_t)(TT & 1) * 16 + pblk) * 4096 + tid * 8;       \
            u32x4 a, b;                                                                          \
            while (1) {                                                                          \
                asm volatile("global_load_dwordx4 %0, %2, off sc1\n\t"                           \
                             "global_load_dwordx4 %1, %2, off offset:16 sc1\n\t"                 \
                             "s_waitcnt vmcnt(0)"                                                \
                             : "=v"(a), "=v"(b) : "v"(pp) : "memory");                           \
                bool ok = (a.x & 0xffffu) == tg && (a.y & 0xffffu) == tg &&                      \
                          (a.z & 0xffffu) == tg && (a.w & 0xffffu) == tg &&                      \
                          (b.x & 0xffffu) == tg && (b.y & 0xffffu) == tg &&                      \
                          (b.z & 0xffffu) == tg && (b.w & 0xffffu) == tg;                        \
                if (ok) break;                                                                   \
            }                                                                                    \
            unsigned int* ld = (unsigned int*)&hl[TT & 1][pbatch][pcol];                         \
            ld[0] = (a.x >> 16) | (a.y & 0xffff0000u);                                           \
            ld[1] = (a.z >> 16) | (a.w & 0xffff0000u);                                           \
            ld[2] = (b.x >> 16) | (b.y & 0xffff0000u);                                           \
            ld[3] = (b.z >> 16) | (b.w & 0xffff0000u);                                           \
        }                                                                                        \
        /* prefetch pre[TT+2] AFTER poll so next poll's vmcnt(0) finds a drained queue */        \
        int tn = (TT + 2 < Tn) ? TT + 2 : Tn - 1;                                                \
        unsigned long long n0 = *(const unsigned long long*)(preP + (size_t)tn * (Bn * Hn));     \
        unsigned long long n1 = *(const unsigned long long*)(preP + (size_t)tn * (Bn * Hn) + 16);\
        asm volatile("s_waitcnt lgkmcnt(0)\n\ts_barrier" ::: "memory"); /* B: partner ready */   \
        if (TT > 0) {                                                                            \
            if (go == 0) MFMA8(8) else MFMA8(0)      /* phase 2: partner half */                 \
        }                                                                                        \
        union { unsigned long long u; unsigned short s[4]; } p0, p1;                             \
        p0.u = P0; p1.u = P1;                                                                    \
        float h0 = tanh_fast(acc0[0] + bf2f(p0.s[0]));                                           \
        float h1 = tanh_fast(acc0[1] + bf2f(p0.s[1]));                                           \
        float h2 = tanh_fast(acc0[2] + bf2f(p0.s[2]));                                           \
        float h3 = tanh_fast(acc0[3] + bf2f(p0.s[3]));                                           \
        float h4 = tanh_fast(acc1[0] + bf2f(p1.s[0]));                                           \
        float h5 = tanh_fast(acc1[1] + bf2f(p1.s[1]));                                           \
        float h6 = tanh_fast(acc1[2] + bf2f(p1.s[2]));                                           \
        float h7 = tanh_fast(acc1[3] + bf2f(p1.s[3]));                                           \
        unsigned int b0 = f2bf(h0), b1 = f2bf(h1), b2 = f2bf(h2), b3 = f2bf(h3);                 \
        unsigned int b4 = f2bf(h4), b5 = f2bf(h5), b6 = f2bf(h6), b7 = f2bf(h7);                 \
        unsigned tv = (unsigned)(fbase + TT + 1);                                                \
        u32x4 s0 = { (b0 << 16) | tv, (b1 << 16) | tv, (b2 << 16) | tv, (b3 << 16) | tv };       \
        u32x4 s1 = { (b4 << 16) | tv, (b5 << 16) | tv, (b6 << 16) | tv, (b7 << 16) | tv };       \
        unsigned int* wp = ex + ((size_t)((TT + 1) & 1) * 16 + myblk) * 4096 + r * 256 + w * 32 + g * 4; \
        asm volatile("global_store_dwordx4 %0, %1, off sc1\n\t"                                  \
                     "global_store_dwordx4 %0, %2, off offset:64 sc1"                            \
                     :: "v"(wp), "v"(s0), "v"(s1) : "memory");                                   \
        {                                                                                        \
            u32x2 v0 = { b0 | (b1 << 16), b2 | (b3 << 16) };                                     \
            u32x2 v1 = { b4 | (b5 << 16), b6 | (b7 << 16) };                                     \
            *(u32x2*)&hl[(TT + 1) & 1][r][ob + g * 4] = v0;                                      \
            *(u32x2*)&hl[(TT + 1) & 1][r][ob + 16 + g * 4] = v1;                                 \
        }                                                                                        \
        if (hsP) {                                                                               \
            union { unsigned int u[2]; unsigned long long v; } o0, o1;                           \
            o0.u[0] = b0 | (b1 << 16); o0.u[1] = b2 | (b3 << 16);                                \
            o1.u[0] = b4 | (b5 << 16); o1.u[1] = b6 | (b7 << 16);                                \
            *(unsigned long long*)(hsP + (size_t)TT * (Bn * Hn)) = o0.v;                         \
            *(unsigned long long*)(hsP + (size_t)TT * (Bn * Hn) + 16) = o1.v;                    \
        }                                                                                        \
        if (ISLAST && hfin) {                                                                    \
            float* hf = hfin + (size_t)bb * Hn + ob + g * 4;                                     \
            hf[0] = h0; hf[1] = h1; hf[2] = h2; hf[3] = h3;                                      \
            hf[16] = h4; hf[17] = h5; hf[18] = h6; hf[19] = h7;                                  \
        }                                                                                        \
        P0 = n0; P1 = n1;                                                                        \
    }

    for (int t = 0; t < Tn; t += 2) {
        REC_STEP(t, pfA0, pfA1, false)
        REC_STEP((t + 1), pfB0, pfB1, (t + 1 == Tn - 1))
    }
#undef REC_STEP
}

// ---------------- final readout ----------------
__global__ __launch_bounds__(64) void readout_k(const float* __restrict__ hfin,
                                                const float* __restrict__ Who1,
                                                const float* __restrict__ bho1,
                                                float* __restrict__ out) {
    int b = blockIdx.x;
    __shared__ float hv[Hn];
    int tid = threadIdx.x;
    for (int i = tid; i < Hn; i += 64) hv[i] = hfin[(size_t)b * Hn + i];
    __syncthreads();
    if (tid < OUTn) {
        float acc = bho1[tid];
        const float* wrow = Who1 + (size_t)tid * Hn;
#pragma unroll 8
        for (int i = 0; i < Hn; ++i) acc += wrow[i] * hv[i];
        out[b * OUTn + tid] = acc;
    }
}

extern "C" void kernel_launch(void* const* d_in, const int* in_sizes, int n_in,
                              void* d_out, int out_size, void* d_ws, size_t ws_size,
                              hipStream_t stream) {
    const float* inputs = (const float*)d_in[0];
    const float* b_d    = (const float*)d_in[1];
    const float* W_emb  = (const float*)d_in[2];
    const float* b_emb  = (const float*)d_in[3];
    const float* W_ih0  = (const float*)d_in[4];
    const float* b_ih0  = (const float*)d_in[5];
    const float* W_hh0  = (const float*)d_in[6];
    const float* b_hh0  = (const float*)d_in[7];
    const float* W_ho0  = (const float*)d_in[8];
    const float* b_ho0  = (const float*)d_in[9];
    const float* W_ih1  = (const float*)d_in[10];
    const float* b_ih1  = (const float*)d_in[11];
    const float* W_hh1  = (const float*)d_in[12];
    const float* b_hh1  = (const float*)d_in[13];
    const float* W_ho1  = (const float*)d_in[14];
    const float* b_ho1  = (const float*)d_in[15];

    char* ws = (char*)d_ws;
    size_t off = 0;
    auto alloc = [&](size_t bytes) {
        void* p = ws + off;
        off += (bytes + 255) & ~(size_t)255;
        return p;
    };
    unsigned short* B    = (unsigned short*)alloc(134217728); // resident [T,B,H] bf16
    unsigned short* Hf   = (unsigned short*)alloc(67108864);  // half-T bounce
    unsigned short* inb  = (unsigned short*)alloc(8388608);
    unsigned short* Wemb = (unsigned short*)alloc(32768);
    unsigned short* Wih0 = (unsigned short*)alloc(524288);
    unsigned short* Whh0 = (unsigned short*)alloc(524288);
    unsigned short* Who0 = (unsigned short*)alloc(524288);
    unsigned short* Wih1 = (unsigned short*)alloc(524288);
    unsigned short* Whh1 = (unsigned short*)alloc(524288);
    float* bias0 = (float*)alloc(2048);
    float* bias1 = (float*)alloc(2048);
    float* piB   = (float*)alloc(131072);
    unsigned int* ex = (unsigned int*)alloc(524288);          // [2][16][16][256] u32
    float* hfin = (float*)alloc(262144);
    (void)ws_size; (void)in_sizes; (void)n_in; (void)out_size;

    unsigned short* B_hi = B + (size_t)512 * Bn * Hn;
    const size_t halfBytes = 67108864;
    const int Mh = 512 * Bn;

    hipMemsetAsync(ex, 0, 524288, stream);
    cvt_k<<<4096, 256, 0, stream>>>(inputs, inb, 1048576);
    cvt_k<<<16,   256, 0, stream>>>(W_emb, Wemb, 4096);
    cvt_k<<<256,  256, 0, stream>>>(W_ih0, Wih0, 65536);
    cvt_k<<<256,  256, 0, stream>>>(W_hh0, Whh0, 65536);
    cvt_k<<<256,  256, 0, stream>>>(W_ho0, Who0, 65536);
    cvt_k<<<256,  256, 0, stream>>>(W_ih1, Wih1, 65536);
    cvt_k<<<256,  256, 0, stream>>>(W_hh1, Whh1, 65536);
    prep_small<<<1, 512, 0, stream>>>(b_d, b_ih0, b_hh0, b_ih1, b_hh1, piB, bias0, bias1);

    // ---- layer 0 ----
    gemm_bt<<<4096, 256, 0, stream>>>(inb, Wemb, B, b_emb, Tn * Bn, Hn, INn);    // B = x
    filt_k<<<dim3(8, 4, 128), 256, 0, stream>>>(B, piB, Hf, 512);
    gemm_bt<<<2048, 256, 0, stream>>>(Hf, Wih0, B_hi, bias0, Mh, Hn, Hn);        // B_hi = pre0_hi
    filt_k<<<dim3(8, 4, 128), 256, 0, stream>>>(B, piB, Hf, 0);
    gemm_bt<<<2048, 256, 0, stream>>>(Hf, Wih0, B, bias0, Mh, Hn, Hn);           // B_lo = pre0_lo
    rec18_k<<<16, 512, 0, stream>>>(Whh0, B, B, nullptr, ex, 0);                 // B = hs0 (in place)
    gemm_bt<<<2048, 256, 0, stream>>>(B_hi, Who0, Hf, b_ho0, Mh, Hn, Hn);
    hipMemcpyAsync(B_hi, Hf, halfBytes, hipMemcpyDeviceToDevice, stream);
    gemm_bt<<<2048, 256, 0, stream>>>(B, Who0, Hf, b_ho0, Mh, Hn, Hn);
    hipMemcpyAsync(B, Hf, halfBytes, hipMemcpyDeviceToDevice, stream);           // B = y0
    // ---- layer 1 ----
    filt_k<<<dim3(8, 4, 128), 256, 0, stream>>>(B, piB, Hf, 512);
    gemm_bt<<<2048, 256, 0, stream>>>(Hf, Wih1, B_hi, bias1, Mh, Hn, Hn);        // B_hi = pre1_hi
    filt_k<<<dim3(8, 4, 128), 256, 0, stream>>>(B, piB, Hf, 0);
    gemm_bt<<<2048, 256, 0, stream>>>(Hf, Wih1, B, bias1, Mh, Hn, Hn);           // B_lo = pre1_lo
    rec18_k<<<16, 512, 0, stream>>>(Whh1, B, nullptr, hfin, ex, 1024);
    readout_k<<<128, 64, 0, stream>>>(hfin, W_ho1, b_ho1, (float*)d_out);
}

// Round 17
// 5372.138 us; speedup vs baseline: 2.5685x; 1.0360x over previous
//
#include <hip/hip_runtime.h>
#include <hip/hip_bf16.h>

#define Tn 1024
#define Bn 128
#define INn 32
#define Hn 512
#define OUTn 32
#define Kn 64
#define LPAD 536

typedef __attribute__((ext_vector_type(8))) __bf16 bf16x8;
typedef __attribute__((ext_vector_type(4))) float f32x4;
typedef __attribute__((ext_vector_type(4))) unsigned int u32x4;
typedef __attribute__((ext_vector_type(2))) unsigned int u32x2;

typedef const __attribute__((address_space(1))) void* gas_p;
typedef __attribute__((address_space(3))) void* las_p;

static __device__ __forceinline__ float bf2f(unsigned short u) {
    union { unsigned int i; float f; } c; c.i = ((unsigned int)u) << 16; return c.f;
}
static __device__ __forceinline__ unsigned short f2bf(float f) {
    union { float f; unsigned int i; } c; c.f = f;
    unsigned int x = c.i;
    return (unsigned short)((x + 0x7fffu + ((x >> 16) & 1u)) >> 16);
}
static __device__ __forceinline__ float tanh_fast(float x) {
    float xc = fminf(fmaxf(x, -10.f), 10.f);
    float e = __expf(2.f * xc);
    return (e - 1.f) * __builtin_amdgcn_rcpf(e + 1.f);
}

// ---------------- f32 -> bf16 convert (n divisible by 4) ----------------
__global__ __launch_bounds__(256) void cvt_k(const float* __restrict__ in,
                                             unsigned short* __restrict__ out, int n4) {
    int i = blockIdx.x * 256 + threadIdx.x;
    if (i < n4) {
        float4 v = ((const float4*)in)[i];
        ushort4 o;
        o.x = f2bf(v.x); o.y = f2bf(v.y); o.z = f2bf(v.z); o.w = f2bf(v.w);
        ((ushort4*)out)[i] = o;
    }
}

// ---------------- pi coefficients + combined biases ----------------
__global__ __launch_bounds__(512) void prep_small(const float* __restrict__ b_d,
                                                  const float* __restrict__ bih0, const float* __restrict__ bhh0,
                                                  const float* __restrict__ bih1, const float* __restrict__ bhh1,
                                                  float* __restrict__ pi, float* __restrict__ bias0,
                                                  float* __restrict__ bias1) {
    int i = threadIdx.x;
    float d = 0.5f / (1.0f + expf(-b_d[i]));
    float c = 1.0f;
    for (int j = 1; j <= Kn; ++j) {
        c *= ((float)(j - 1) - d) / (float)j;
        pi[(j - 1) * Hn + i] = c;
    }
    bias0[i] = bih0[i] + bhh0[i];
    bias1[i] = bih1[i] + bhh1[i];
}

// ---------------- GEMM: C[M,N](bf16) = A[M,K](bf16) . Bm[N,K](bf16)^T + bias[N](f32) --------
__global__ __launch_bounds__(256, 2) void gemm_bt(const unsigned short* __restrict__ A,
                                                  const unsigned short* __restrict__ Bm,
                                                  unsigned short* __restrict__ C,
                                                  const float* __restrict__ bias,
                                                  int M, int N, int K) {
    __shared__ unsigned short As[128 * 32];
    __shared__ unsigned short Bs[128 * 32];
    int ntile = N >> 7;
    int bm = blockIdx.x / ntile;
    int bn = blockIdx.x - bm * ntile;
    size_t m0 = (size_t)bm << 7;
    int n0 = bn << 7;
    int tid = threadIdx.x;
    int lane = tid & 63, w = tid >> 6;
    int wm = w >> 1, wn = w & 1;
    int r = lane & 15, g = lane >> 4;
    int srow = tid >> 2, sblk = tid & 3;
    f32x4 acc[4][4] = {};
    for (int k0 = 0; k0 < K; k0 += 32) {
#pragma unroll
        for (int it = 0; it < 2; ++it) {
            const unsigned short* ga = A + (m0 + it * 64 + srow) * (size_t)K + k0 + sblk * 8;
            __builtin_amdgcn_global_load_lds((gas_p)ga, (las_p)((char*)As + it * 4096 + w * 1024), 16, 0, 0);
            const unsigned short* gbp = Bm + ((size_t)(n0 + it * 64 + srow)) * (size_t)K + k0 + sblk * 8;
            __builtin_amdgcn_global_load_lds((gas_p)gbp, (las_p)((char*)Bs + it * 4096 + w * 1024), 16, 0, 0);
        }
        __syncthreads();
        bf16x8 af[4], bfr[4];
#pragma unroll
        for (int m = 0; m < 4; ++m) af[m] = *(const bf16x8*)&As[(wm * 64 + m * 16 + r) * 32 + g * 8];
#pragma unroll
        for (int n = 0; n < 4; ++n) bfr[n] = *(const bf16x8*)&Bs[(wn * 64 + n * 16 + r) * 32 + g * 8];
#pragma unroll
        for (int m = 0; m < 4; ++m)
#pragma unroll
            for (int n = 0; n < 4; ++n)
                acc[m][n] = __builtin_amdgcn_mfma_f32_16x16x32_bf16(af[m], bfr[n], acc[m][n], 0, 0, 0);
        __syncthreads();
    }
#pragma unroll
    for (int n = 0; n < 4; ++n) {
        int col = n0 + wn * 64 + n * 16 + r;
        float bv = bias[col];
#pragma unroll
        for (int m = 0; m < 4; ++m) {
            size_t row0 = m0 + wm * 64 + m * 16 + g * 4;
#pragma unroll
            for (int q = 0; q < 4; ++q)
                C[(row0 + q) * (size_t)N + col] = f2bf(acc[m][n][q] + bv);
        }
    }
}

// ---------------- causal fractional-diff filter (chunked over t) ----------------
__global__ __launch_bounds__(256, 2) void filt_k(const unsigned short* __restrict__ X,
                                                 const float* __restrict__ Pi,
                                                 unsigned short* __restrict__ Y, int t_off) {
    int tid = threadIdx.x;
    int il = tid & 63, ts = tid >> 6;
    int i = blockIdx.x * 64 + il;
    int b = blockIdx.z;
    int tbase = t_off + blockIdx.y * 128 + ts * 32;
    float xr[96];
#pragma unroll
    for (int k2 = 0; k2 < 96; ++k2) {
        int t = tbase - 64 + k2;
        xr[k2] = (t >= 0) ? bf2f(X[(size_t)t * (Bn * Hn) + b * Hn + i]) : 0.0f;
    }
    float acc[32];
#pragma unroll
    for (int tt = 0; tt < 32; ++tt) acc[tt] = xr[64 + tt];
#pragma unroll
    for (int j = 1; j <= 64; ++j) {
        float p = Pi[(j - 1) * Hn + i];
#pragma unroll
        for (int tt = 0; tt < 32; ++tt) acc[tt] += p * xr[64 + tt - j];
    }
#pragma unroll
    for (int tt = 0; tt < 32; ++tt)
        Y[(size_t)(tbase - t_off + tt) * (Bn * Hn) + b * Hn + i] = f2bf(acc[tt]);
}

// ---------------- recurrence v19: rec18 + L2-scope polls (sc0 first, sc1 fallback) ---------
// Publish stays sc1 (device scope: writes through the shared per-XCD L2 to IC -- correct
// at ANY wg placement). Poll first tries sc0 (SE scope: bypasses reader L1, reads the
// SHARED L2 -- fresh when partners are same-XCD per bid%8 round-robin, ~3x lower RT than
// IC), then ALTERNATES sc1/sc0 on retry so cross-XCD placement still makes progress
// (sc1 reads IC, where all publishes land). Polls issue right after barrier A so their RT
// hides under the own-half MFMAs (tied-operand vmcnt wait + sched_barrier, rule #18).
// Everything else identical to rec18 (round-16, passing).
#define MFMA8(K0)                                                                              \
    {                                                                                          \
        _Pragma("unroll") for (int kk = 0; kk < 8; ++kk) {                                     \
            bf16x8 bf = *(const bf16x8*)(hrow + (K0 + kk) * 32 + g * 8);                       \
            acc0 = __builtin_amdgcn_mfma_f32_16x16x32_bf16(wreg0[K0 + kk], bf, acc0, 0, 0, 0); \
            acc1 = __builtin_amdgcn_mfma_f32_16x16x32_bf16(wreg1[K0 + kk], bf, acc1, 0, 0, 0); \
        }                                                                                      \
    }

__global__ __launch_bounds__(512, 1) void rec19_k(const unsigned short* __restrict__ W,
                                                  const unsigned short* pre,
                                                  unsigned short* hs,
                                                  float* __restrict__ hfin,
                                                  unsigned int* ex, int fbase) {
    __shared__ unsigned short hl[2][16][LPAD];
    int bid = blockIdx.x;
    int gb = bid & 7, go = bid >> 3;
    int tid = threadIdx.x, lane = tid & 63, w = tid >> 6;
    int r = lane & 15, g = lane >> 4;
    int ob = go * 256 + w * 32;
    bf16x8 wreg0[16], wreg1[16];
#pragma unroll
    for (int kk = 0; kk < 16; ++kk) {
        wreg0[kk] = *(const bf16x8*)(W + (size_t)(ob + r) * Hn + kk * 32 + g * 8);
        wreg1[kk] = *(const bf16x8*)(W + (size_t)(ob + 16 + r) * Hn + kk * 32 + g * 8);
    }
    int bb = gb * 16 + r;
    const unsigned short* preP = pre + (size_t)bb * Hn + ob + g * 4;
    unsigned short* hsP = hs ? hs + (size_t)bb * Hn + ob + g * 4 : (unsigned short*)0;
    int myblk = gb * 2 + go, pblk = gb * 2 + (go ^ 1);
    int pbatch = tid >> 5;
    int pcol = (go ^ 1) * 256 + (tid & 31) * 8;
    unsigned long long pfA0 = *(const unsigned long long*)(preP);
    unsigned long long pfA1 = *(const unsigned long long*)(preP + 16);
    unsigned long long pfB0 = *(const unsigned long long*)(preP + (size_t)(Bn * Hn));
    unsigned long long pfB1 = *(const unsigned long long*)(preP + (size_t)(Bn * Hn) + 16);

#define CHK8()                                                                                   \
    ((a.x & 0xffffu) == tg && (a.y & 0xffffu) == tg &&                                           \
     (a.z & 0xffffu) == tg && (a.w & 0xffffu) == tg &&                                           \
     (b.x & 0xffffu) == tg && (b.y & 0xffffu) == tg &&                                           \
     (b.z & 0xffffu) == tg && (b.w & 0xffffu) == tg)

#define REC_STEP(TT, P0, P1, ISLAST)                                                             \
    {                                                                                            \
        asm volatile("s_waitcnt lgkmcnt(0)\n\ts_barrier" ::: "memory"); /* A: own half ready */  \
        f32x4 acc0 = {0.f, 0.f, 0.f, 0.f}, acc1 = {0.f, 0.f, 0.f, 0.f};                          \
        const unsigned short* hrow = &hl[TT & 1][r][0];                                          \
        if (TT > 0) {                                                                            \
            unsigned tg = (unsigned)(fbase + TT);                                                \
            const unsigned int* pp = ex + ((size_t)(TT & 1) * 16 + pblk) * 4096 + tid * 8;       \
            u32x4 a, b;                                                                          \
            /* issue first attempt (sc0 = shared-L2 scope) BEFORE own-MFMA: RT hides */          \
            asm volatile("global_load_dwordx4 %0, %2, off sc0\n\t"                               \
                         "global_load_dwordx4 %1, %2, off offset:16 sc0"                         \
                         : "=v"(a), "=v"(b) : "v"(pp) : "memory");                               \
            if (go == 0) MFMA8(0) else MFMA8(8)      /* phase 1: own half */                     \
            asm volatile("s_waitcnt vmcnt(0)" : "+v"(a), "+v"(b) :: "memory");                   \
            __builtin_amdgcn_sched_barrier(0);                                                   \
            while (!CHK8()) {                                                                    \
                /* sc1 attempt: reads IC, guarantees progress at any wg placement */             \
                asm volatile("global_load_dwordx4 %0, %2, off sc1\n\t"                           \
                             "global_load_dwordx4 %1, %2, off offset:16 sc1\n\t"                 \
                             "s_waitcnt vmcnt(0)"                                                \
                             : "=v"(a), "=v"(b) : "v"(pp) : "memory");                           \
                if (CHK8()) break;                                                               \
                asm volatile("global_load_dwordx4 %0, %2, off sc0\n\t"                           \
                             "global_load_dwordx4 %1, %2, off offset:16 sc0\n\t"                 \
                             "s_waitcnt vmcnt(0)"                                                \
                             : "=v"(a), "=v"(b) : "v"(pp) : "memory");                           \
            }                                                                                    \
            __builtin_amdgcn_sched_barrier(0);                                                   \
            unsigned int* ld = (unsigned int*)&hl[TT & 1][pbatch][pcol];                         \
            ld[0] = (a.x >> 16) | (a.y & 0xffff0000u);                                           \
            ld[1] = (a.z >> 16) | (a.w & 0xffff0000u);                                           \
            ld[2] = (b.x >> 16) | (b.y & 0xffff0000u);                                           \
            ld[3] = (b.z >> 16) | (b.w & 0xffff0000u);                                           \
        }                                                                                        \
        /* prefetch pre[TT+2] AFTER poll so next poll's vmcnt(0) finds a drained queue */        \
        int tn = (TT + 2 < Tn) ? TT + 2 : Tn - 1;                                                \
        unsigned long long n0 = *(const unsigned long long*)(preP + (size_t)tn * (Bn * Hn));     \
        unsigned long long n1 = *(const unsigned long long*)(preP + (size_t)tn * (Bn * Hn) + 16);\
        asm volatile("s_waitcnt lgkmcnt(0)\n\ts_barrier" ::: "memory"); /* B: partner ready */   \
        if (TT > 0) {                                                                            \
            if (go == 0) MFMA8(8) else MFMA8(0)      /* phase 2: partner half */                 \
        }                                                                                        \
        union { unsigned long long u; unsigned short s[4]; } p0, p1;                             \
        p0.u = P0; p1.u = P1;                                                                    \
        float h0 = tanh_fast(acc0[0] + bf2f(p0.s[0]));                                           \
        float h1 = tanh_fast(acc0[1] + bf2f(p0.s[1]));                                           \
        float h2 = tanh_fast(acc0[2] + bf2f(p0.s[2]));                                           \
        float h3 = tanh_fast(acc0[3] + bf2f(p0.s[3]));                                           \
        float h4 = tanh_fast(acc1[0] + bf2f(p1.s[0]));                                           \
        float h5 = tanh_fast(acc1[1] + bf2f(p1.s[1]));                                           \
        float h6 = tanh_fast(acc1[2] + bf2f(p1.s[2]));                                           \
        float h7 = tanh_fast(acc1[3] + bf2f(p1.s[3]));                                           \
        unsigned int b0 = f2bf(h0), b1 = f2bf(h1), b2 = f2bf(h2), b3 = f2bf(h3);                 \
        unsigned int b4 = f2bf(h4), b5 = f2bf(h5), b6 = f2bf(h6), b7 = f2bf(h7);                 \
        unsigned tv = (unsigned)(fbase + TT + 1);                                                \
        u32x4 s0 = { (b0 << 16) | tv, (b1 << 16) | tv, (b2 << 16) | tv, (b3 << 16) | tv };       \
        u32x4 s1 = { (b4 << 16) | tv, (b5 << 16) | tv, (b6 << 16) | tv, (b7 << 16) | tv };       \
        unsigned int* wp = ex + ((size_t)((TT + 1) & 1) * 16 + myblk) * 4096 + r * 256 + w * 32 + g * 4; \
        asm volatile("global_store_dwordx4 %0, %1, off sc1\n\t"                                  \
                     "global_store_dwordx4 %0, %2, off offset:64 sc1"                            \
                     :: "v"(wp), "v"(s0), "v"(s1) : "memory");                                   \
        {                                                                                        \
            u32x2 v0 = { b0 | (b1 << 16), b2 | (b3 << 16) };                                     \
            u32x2 v1 = { b4 | (b5 << 16), b6 | (b7 << 16) };                                     \
            *(u32x2*)&hl[(TT + 1) & 1][r][ob + g * 4] = v0;                                      \
            *(u32x2*)&hl[(TT + 1) & 1][r][ob + 16 + g * 4] = v1;                                 \
        }                                                                                        \
        if (hsP) {                                                                               \
            union { unsigned int u[2]; unsigned long long v; } o0, o1;                           \
            o0.u[0] = b0 | (b1 << 16); o0.u[1] = b2 | (b3 << 16);                                \
            o1.u[0] = b4 | (b5 << 16); o1.u[1] = b6 | (b7 << 16);                                \
            *(unsigned long long*)(hsP + (size_t)TT * (Bn * Hn)) = o0.v;                         \
            *(unsigned long long*)(hsP + (size_t)TT * (Bn * Hn) + 16) = o1.v;                    \
        }                                                                                        \
        if (ISLAST && hfin) {                                                                    \
            float* hf = hfin + (size_t)bb * Hn + ob + g * 4;                                     \
            hf[0] = h0; hf[1] = h1; hf[2] = h2; hf[3] = h3;                                      \
            hf[16] = h4; hf[17] = h5; hf[18] = h6; hf[19] = h7;                                  \
        }                                                                                        \
        P0 = n0; P1 = n1;                                                                        \
    }

    for (int t = 0; t < Tn; t += 2) {
        REC_STEP(t, pfA0, pfA1, false)
        REC_STEP((t + 1), pfB0, pfB1, (t + 1 == Tn - 1))
    }
#undef REC_STEP
#undef CHK8
}

// ---------------- final readout ----------------
__global__ __launch_bounds__(64) void readout_k(const float* __restrict__ hfin,
                                                const float* __restrict__ Who1,
                                                const float* __restrict__ bho1,
                                                float* __restrict__ out) {
    int b = blockIdx.x;
    __shared__ float hv[Hn];
    int tid = threadIdx.x;
    for (int i = tid; i < Hn; i += 64) hv[i] = hfin[(size_t)b * Hn + i];
    __syncthreads();
    if (tid < OUTn) {
        float acc = bho1[tid];
        const float* wrow = Who1 + (size_t)tid * Hn;
#pragma unroll 8
        for (int i = 0; i < Hn; ++i) acc += wrow[i] * hv[i];
        out[b * OUTn + tid] = acc;
    }
}

extern "C" void kernel_launch(void* const* d_in, const int* in_sizes, int n_in,
                              void* d_out, int out_size, void* d_ws, size_t ws_size,
                              hipStream_t stream) {
    const float* inputs = (const float*)d_in[0];
    const float* b_d    = (const float*)d_in[1];
    const float* W_emb  = (const float*)d_in[2];
    const float* b_emb  = (const float*)d_in[3];
    const float* W_ih0  = (const float*)d_in[4];
    const float* b_ih0  = (const float*)d_in[5];
    const float* W_hh0  = (const float*)d_in[6];
    const float* b_hh0  = (const float*)d_in[7];
    const float* W_ho0  = (const float*)d_in[8];
    const float* b_ho0  = (const float*)d_in[9];
    const float* W_ih1  = (const float*)d_in[10];
    const float* b_ih1  = (const float*)d_in[11];
    const float* W_hh1  = (const float*)d_in[12];
    const float* b_hh1  = (const float*)d_in[13];
    const float* W_ho1  = (const float*)d_in[14];
    const float* b_ho1  = (const float*)d_in[15];

    char* ws = (char*)d_ws;
    size_t off = 0;
    auto alloc = [&](size_t bytes) {
        void* p = ws + off;
        off += (bytes + 255) & ~(size_t)255;
        return p;
    };
    unsigned short* B    = (unsigned short*)alloc(134217728); // resident [T,B,H] bf16
    unsigned short* Hf   = (unsigned short*)alloc(67108864);  // half-T bounce
    unsigned short* inb  = (unsigned short*)alloc(8388608);
    unsigned short* Wemb = (unsigned short*)alloc(32768);
    unsigned short* Wih0 = (unsigned short*)alloc(524288);
    unsigned short* Whh0 = (unsigned short*)alloc(524288);
    unsigned short* Who0 = (unsigned short*)alloc(524288);
    unsigned short* Wih1 = (unsigned short*)alloc(524288);
    unsigned short* Whh1 = (unsigned short*)alloc(524288);
    float* bias0 = (float*)alloc(2048);
    float* bias1 = (float*)alloc(2048);
    float* piB   = (float*)alloc(131072);
    unsigned int* ex = (unsigned int*)alloc(524288);          // [2][16][16][256] u32
    float* hfin = (float*)alloc(262144);
    (void)ws_size; (void)in_sizes; (void)n_in; (void)out_size;

    unsigned short* B_hi = B + (size_t)512 * Bn * Hn;
    const size_t halfBytes = 67108864;
    const int Mh = 512 * Bn;

    hipMemsetAsync(ex, 0, 524288, stream);
    cvt_k<<<4096, 256, 0, stream>>>(inputs, inb, 1048576);
    cvt_k<<<16,   256, 0, stream>>>(W_emb, Wemb, 4096);
    cvt_k<<<256,  256, 0, stream>>>(W_ih0, Wih0, 65536);
    cvt_k<<<256,  256, 0, stream>>>(W_hh0, Whh0, 65536);
    cvt_k<<<256,  256, 0, stream>>>(W_ho0, Who0, 65536);
    cvt_k<<<256,  256, 0, stream>>>(W_ih1, Wih1, 65536);
    cvt_k<<<256,  256, 0, stream>>>(W_hh1, Whh1, 65536);
    prep_small<<<1, 512, 0, stream>>>(b_d, b_ih0, b_hh0, b_ih1, b_hh1, piB, bias0, bias1);

    // ---- layer 0 ----
    gemm_bt<<<4096, 256, 0, stream>>>(inb, Wemb, B, b_emb, Tn * Bn, Hn, INn);    // B = x
    filt_k<<<dim3(8, 4, 128), 256, 0, stream>>>(B, piB, Hf, 512);
    gemm_bt<<<2048, 256, 0, stream>>>(Hf, Wih0, B_hi, bias0, Mh, Hn, Hn);        // B_hi = pre0_hi
    filt_k<<<dim3(8, 4, 128), 256, 0, stream>>>(B, piB, Hf, 0);
    gemm_bt<<<2048, 256, 0, stream>>>(Hf, Wih0, B, bias0, Mh, Hn, Hn);           // B_lo = pre0_lo
    rec19_k<<<16, 512, 0, stream>>>(Whh0, B, B, nullptr, ex, 0);                 // B = hs0 (in place)
    gemm_bt<<<2048, 256, 0, stream>>>(B_hi, Who0, Hf, b_ho0, Mh, Hn, Hn);
    hipMemcpyAsync(B_hi, Hf, halfBytes, hipMemcpyDeviceToDevice, stream);
    gemm_bt<<<2048, 256, 0, stream>>>(B, Who0, Hf, b_ho0, Mh, Hn, Hn);
    hipMemcpyAsync(B, Hf, halfBytes, hipMemcpyDeviceToDevice, stream);           // B = y0
    // ---- layer 1 ----
    filt_k<<<dim3(8, 4, 128), 256, 0, stream>>>(B, piB, Hf, 512);
    gemm_bt<<<2048, 256, 0, stream>>>(Hf, Wih1, B_hi, bias1, Mh, Hn, Hn);        // B_hi = pre1_hi
    filt_k<<<dim3(8, 4, 128), 256, 0, stream>>>(B, piB, Hf, 0);
    gemm_bt<<<2048, 256, 0, stream>>>(Hf, Wih1, B, bias1, Mh, Hn, Hn);           // B_lo = pre1_lo
    rec19_k<<<16, 512, 0, stream>>>(Whh1, B, nullptr, hfin, ex, 1024);
    readout_k<<<128, 64, 0, stream>>>(hfin, W_ho1, b_ho1, (float*)d_out);
}